// Round 1
// 200.326 us; speedup vs baseline: 1.1542x; 1.1542x over previous
//
#include <hip/hip_runtime.h>

#define DF 64
#define ELLK 32     // per-node ELL width; ovf list handles deg>32 exactly
#define NB 256      // dst-range buckets for the binned build
#define BSTR 7168   // pairs per bucket (avg 6250, sd ~79 -> 11.6 sigma margin)
#define NPB 400     // max nodes per bucket (ceil(100000/256)=391)
#define NSL 4       // feature slices (16 feats each); sub-table 3.2 MB -> XCD L2

typedef __attribute__((ext_vector_type(8))) short bf16x8;  // MFMA A/B frag
typedef __attribute__((ext_vector_type(4))) float f32x4;   // MFMA C/D frag

__device__ __forceinline__ unsigned short bf16rne(float f) {
    unsigned u = __float_as_uint(f);
    unsigned r = u + 0x7fffu + ((u >> 16) & 1u);
    return (unsigned short)(r >> 16);
}
__device__ __forceinline__ float b2f(unsigned short u) {
    return __uint_as_float((unsigned)u << 16);
}

// ---------------------------------------------------------------------------
// K1: h (fp32) -> hbs slice-major bf16, layout [NSL][N+1][16] (slice s =
// feats [16s,16s+16)). Row N of each slice is a ZERO row: the gather clamps
// invalid ELL slots to it, making the inner loop branch-free.
// Also zeroes bucket cursors + ovfcnt.
// ---------------------------------------------------------------------------
__global__ __launch_bounds__(256) void conv_zero(
    const float* __restrict__ h, unsigned short* __restrict__ hbs,
    int* __restrict__ gcur, int* __restrict__ ovfcnt, int N)
{
    int tid = blockIdx.x * 256 + threadIdx.x;
    if (tid < NB) gcur[tid] = 0;
    if (tid == NB) *ovfcnt = 0;
    if (tid < NSL) {  // zero sentinel row per slice
        unsigned short* zp = &hbs[((size_t)tid * (N + 1) + N) * 16];
        ushort4 z = {0, 0, 0, 0};
        *(ushort4*)zp = z; *(ushort4*)(zp + 4) = z;
        *(ushort4*)(zp + 8) = z; *(ushort4*)(zp + 12) = z;
    }
    if (tid < N * 8) {
        int n = tid >> 3, s8 = tid & 7;           // s8 = 8-feat sub-slice
        const float* hp = &h[(size_t)n * DF + s8 * 8];
        float4 v0 = *(const float4*)hp;
        float4 v1 = *(const float4*)(hp + 4);
        ushort4 o0, o1;
        o0.x = bf16rne(v0.x); o0.y = bf16rne(v0.y); o0.z = bf16rne(v0.z); o0.w = bf16rne(v0.w);
        o1.x = bf16rne(v1.x); o1.y = bf16rne(v1.y); o1.z = bf16rne(v1.z); o1.w = bf16rne(v1.w);
        // slice = s8>>1, 8-feat half = s8&1
        unsigned short* op = &hbs[((size_t)(s8 >> 1) * (N + 1) + n) * 16 + (s8 & 1) * 8];
        *(ushort4*)op = o0;
        *(ushort4*)(op + 4) = o1;
    }
}

// ---------------------------------------------------------------------------
// K2a: bin edges into NB dst-range buckets. Per block: LDS histogram ->
// one global atomicAdd per bucket reserves an EXCLUSIVE span -> packed u32
// (local_node<<17 | src) written into the span. Each block's write frontier
// is ~16 KB (256 buckets x ~1 line) -> L2 merges fully.
// ---------------------------------------------------------------------------
#define EPT 13  // edges per thread; per block = 13*256 = 3328
__global__ __launch_bounds__(256) void bin_edges(
    const int* __restrict__ src, const int* __restrict__ dst,
    int* __restrict__ gcur, unsigned* __restrict__ pairs,
    int* __restrict__ ovf, int* __restrict__ ovfcnt, int ovfcap, int E, int N)
{
    __shared__ unsigned hist[NB];
    __shared__ unsigned base_s[NB];
    int t = threadIdx.x;
    for (int i = t; i < NB; i += 256) hist[i] = 0;
    __syncthreads();

    int e0 = blockIdx.x * (EPT * 256);
    unsigned pk[EPT];
    #pragma unroll
    for (int k = 0; k < EPT; ++k) {
        int e = e0 + k * 256 + t;
        pk[k] = 0xFFFFFFFFu;
        if (e < E) {
            int d = dst[e];
            unsigned bkt = (unsigned)(((unsigned long long)d * NB) / (unsigned)N);
            unsigned r = atomicAdd(&hist[bkt], 1u);
            pk[k] = (r << 8) | bkt;   // rank < 3328 fits in 24 bits
        }
    }
    __syncthreads();
    for (int i = t; i < NB; i += 256)
        base_s[i] = (unsigned)atomicAdd(&gcur[i], (int)hist[i]);
    __syncthreads();

    #pragma unroll
    for (int k = 0; k < EPT; ++k) {
        if (pk[k] != 0xFFFFFFFFu) {
            int e = e0 + k * 256 + t;
            int d = dst[e], s = src[e];   // re-read (L1/L2 warm)
            unsigned bkt = pk[k] & 255u;
            unsigned pos = base_s[bkt] + (pk[k] >> 8);
            if (pos < BSTR) {
                int lo = (int)(((long long)bkt * N + NB - 1) / NB);
                pairs[(size_t)bkt * BSTR + pos] = ((unsigned)(d - lo) << 17) | (unsigned)s;
            } else {  // bucket span overflow -> exact fallback list
                int p = atomicAdd(ovfcnt, 1);
                if (p < ovfcap) { ovf[2 * p] = d; ovf[2 * p + 1] = s; }
            }
        }
    }
}

// ---------------------------------------------------------------------------
// K2b: build ELL per bucket entirely in LDS (LDS atomics), then write the
// bucket's ELL rows + cnt to global FULLY COALESCED. Columns are stored in
// PERMUTED order p(slot) = (slot&7)*4 | (slot>>3), so the gather's 4 slots
// {nb, nb+8, nb+16, nb+24} are one contiguous int4.
// cnt stores min(count,ELLK); ELLK-overflow edges go to ovf.
// ---------------------------------------------------------------------------
__global__ __launch_bounds__(256) void build_ell(
    const unsigned* __restrict__ pairs, const int* __restrict__ gcur,
    int* __restrict__ cnt, int* __restrict__ ell,
    int* __restrict__ ovf, int* __restrict__ ovfcnt, int ovfcap, int N)
{
    __shared__ int ell_l[NPB * ELLK];  // 51.2 KB
    __shared__ int cnt_l[NPB];
    int b = blockIdx.x, t = threadIdx.x;
    int lo = (int)(((long long)b * N + NB - 1) / NB);
    int hi = (int)(((long long)(b + 1) * N + NB - 1) / NB);
    if (hi > N) hi = N;
    int nn = hi - lo;
    for (int i = t; i < nn; i += 256) cnt_l[i] = 0;
    __syncthreads();

    int count = gcur[b]; if (count > BSTR) count = BSTR;
    const unsigned* pb = &pairs[(size_t)b * BSTR];
    for (int i = t; i < count; i += 256) {
        unsigned p = pb[i];
        int ld = (int)(p >> 17);
        int s  = (int)(p & 131071u);
        int slot = atomicAdd(&cnt_l[ld], 1);
        if (slot < ELLK) {
            ell_l[ld * ELLK + (((slot & 7) << 2) | (slot >> 3))] = s;  // permuted col
        } else {
            int q = atomicAdd(ovfcnt, 1);
            if (q < ovfcap) { ovf[2 * q] = lo + ld; ovf[2 * q + 1] = s; }
        }
    }
    __syncthreads();

    int total = nn * ELLK;
    int* eout = &ell[(size_t)lo * ELLK];
    for (int i = t; i < total; i += 256) eout[i] = ell_l[i];  // coalesced
    for (int i = t; i < nn; i += 256) {
        int c = cnt_l[i];
        cnt[lo + i] = c < ELLK ? c : ELLK;
    }
}

// ---------------------------------------------------------------------------
// K3: feature-sliced gather, 16-feat slices (r12). slice = blockIdx&3 ->
// one slice per XCD (3.2 MB sub-table L2-resident). Wave-iter covers 4
// nodes; per lane: one int4 ELL load (permuted cols) + 4 unconditional
// 16 B gathers (invalid slots clamp to the zero row) -> branch-free body.
// ---------------------------------------------------------------------------
__global__ __launch_bounds__(512) void gather_slice(
    const unsigned short* __restrict__ hbs, const int* __restrict__ cnt,
    const int* __restrict__ ell, unsigned short* __restrict__ csum, int N)
{
    int slice = blockIdx.x & 3;
    int wave = threadIdx.x >> 6, lane = threadIdx.x & 63;
    const int ns = lane >> 4;   // node within wave-iter
    const int q  = lane & 15;
    const int nb = q >> 1;      // neighbor sub-slot 0..7
    const int fp = q & 1;       // 8-feat half of the 16-feat slice
    const unsigned short* tab = hbs + (size_t)slice * (N + 1) * 16;
    unsigned short* cs = csum + (size_t)slice * N * 16;

    int gw = (blockIdx.x >> 2) * 8 + wave;
    int nw = (gridDim.x >> 2) * 8;

    for (int n0 = gw * 4; n0 < N; n0 += nw * 4) {
        int n = n0 + ns;
        bool valid = (n < N);
        int m = valid ? cnt[n] : 0;
        const int* erow = &ell[(size_t)(valid ? n : 0) * ELLK];
        int4 pv = *(const int4*)(erow + nb * 4);   // slots {nb,nb+8,nb+16,nb+24}
        int id0 = (nb      < m) ? pv.x : N;        // N = zero row sentinel
        int id1 = (nb +  8 < m) ? pv.y : N;
        int id2 = (nb + 16 < m) ? pv.z : N;
        int id3 = (nb + 24 < m) ? pv.w : N;

        bf16x8 v0 = *(const bf16x8*)&tab[(size_t)id0 * 16 + fp * 8];
        bf16x8 v1 = *(const bf16x8*)&tab[(size_t)id1 * 16 + fp * 8];
        bf16x8 v2 = *(const bf16x8*)&tab[(size_t)id2 * 16 + fp * 8];
        bf16x8 v3 = *(const bf16x8*)&tab[(size_t)id3 * 16 + fp * 8];

        f32x4 lo, hi;
        #pragma unroll
        for (int i = 0; i < 4; ++i) {
            lo[i] = (b2f((unsigned short)v0[i])     + b2f((unsigned short)v1[i]))
                  + (b2f((unsigned short)v2[i])     + b2f((unsigned short)v3[i]));
            hi[i] = (b2f((unsigned short)v0[4 + i]) + b2f((unsigned short)v1[4 + i]))
                  + (b2f((unsigned short)v2[4 + i]) + b2f((unsigned short)v3[4 + i]));
        }

        #pragma unroll
        for (int msk = 2; msk <= 8; msk <<= 1) {
            #pragma unroll
            for (int i = 0; i < 4; ++i) {
                lo[i] += __shfl_xor(lo[i], msk);
                hi[i] += __shfl_xor(hi[i], msk);
            }
        }

        if (valid && nb == 0) {
            bf16x8 o;
            o[0] = (short)bf16rne(lo[0]); o[1] = (short)bf16rne(lo[1]);
            o[2] = (short)bf16rne(lo[2]); o[3] = (short)bf16rne(lo[3]);
            o[4] = (short)bf16rne(hi[0]); o[5] = (short)bf16rne(hi[1]);
            o[6] = (short)bf16rne(hi[2]); o[7] = (short)bf16rne(hi[3]);
            *(bf16x8*)&cs[(size_t)n * 16 + fp * 8] = o;  // bf16 raw SUM
        }
    }
}

// ---------------------------------------------------------------------------
// K4: MFMA update. [N x 128]@[128 x 64] via 16x16x32 bf16. Fragment
// addressing re-derived for [NSL][N+1][16] hbs / [NSL][N][16] csum:
// global feat g = q*8 (+32 for hi k-tiles) -> slice g>>4, half (q&1)*8.
// ---------------------------------------------------------------------------
__global__ __launch_bounds__(256) void sage_update_mfma(
    const float* __restrict__ h, const float* __restrict__ W,
    const float* __restrict__ b, const int* __restrict__ cnt,
    const unsigned short* __restrict__ hbs,
    const unsigned short* __restrict__ csum,
    const int* __restrict__ ovf, const int* __restrict__ ovfcnt,
    int ovfcap, float* __restrict__ out, int N)
{
    const int lane = threadIdx.x & 63;
    const int wave = threadIdx.x >> 6;
    const int c = lane & 15;
    const int q = lane >> 4;

    bf16x8 bf[4][4];
    #pragma unroll
    for (int nt = 0; nt < 4; ++nt) {
        #pragma unroll
        for (int kt = 0; kt < 4; ++kt) {
            const float* wp = &W[(size_t)(nt * 16 + c) * 128 + kt * 32 + q * 8];
            float4 w0 = *(const float4*)wp;
            float4 w1 = *(const float4*)(wp + 4);
            bf16x8 f;
            f[0] = (short)bf16rne(w0.x); f[1] = (short)bf16rne(w0.y);
            f[2] = (short)bf16rne(w0.z); f[3] = (short)bf16rne(w0.w);
            f[4] = (short)bf16rne(w1.x); f[5] = (short)bf16rne(w1.y);
            f[6] = (short)bf16rne(w1.z); f[7] = (short)bf16rne(w1.w);
            bf[nt][kt] = f;
        }
    }
    float bias[4];
    #pragma unroll
    for (int nt = 0; nt < 4; ++nt) bias[nt] = b[nt * 16 + c];

    int oc = *ovfcnt; if (oc > ovfcap) oc = ovfcap;

    int gwave = blockIdx.x * 4 + wave;
    int nwave = gridDim.x * 4;
    int ntiles = (N + 15) >> 4;
    const int sl0 = q >> 1;          // slice for k-tile 0/1 feats (q*8)
    const int hf  = (q & 1) * 8;     // 8-feat half offset within slice

    for (int tile = gwave; tile < ntiles; tile += nwave) {
        int n0 = tile << 4;
        int nm = n0 + c;
        int nmc = nm < N ? nm : N - 1;
        int deg = cnt[nmc];
        int extra = 0;
        if (oc > 0) {
            for (int t = 0; t < oc; ++t)
                if (ovf[2 * t] == nm) extra++;
        }
        int dtot = deg + extra;
        float inv = 1.0f / fmaxf((float)dtot, 1.0f);

        bf16x8 a0 = *(const bf16x8*)&hbs[((size_t)sl0 * (N + 1) + nmc) * 16 + hf];
        bf16x8 a1 = *(const bf16x8*)&hbs[((size_t)(sl0 + 2) * (N + 1) + nmc) * 16 + hf];
        bf16x8 a2, a3;
        #pragma unroll
        for (int kc = 0; kc < 2; ++kc) {
            int sl = kc * 2 + sl0;
            bf16x8 u = *(const bf16x8*)&csum[((size_t)sl * N + nmc) * 16 + hf];
            float e[8];
            #pragma unroll
            for (int i = 0; i < 8; ++i) e[i] = b2f((unsigned short)u[i]);
            if (oc > 0) {
                for (int t = 0; t < oc; ++t) {
                    if (ovf[2 * t] == nm) {
                        bf16x8 hu = *(const bf16x8*)&hbs[((size_t)sl * (N + 1) + ovf[2 * t + 1]) * 16 + hf];
                        #pragma unroll
                        for (int i = 0; i < 8; ++i) e[i] += b2f((unsigned short)hu[i]);
                    }
                }
            }
            bf16x8 f;
            #pragma unroll
            for (int i = 0; i < 8; ++i) f[i] = (short)bf16rne(e[i] * inv);
            if (kc == 0) a2 = f; else a3 = f;
        }

        f32x4 acc0 = {bias[0], bias[0], bias[0], bias[0]};
        f32x4 acc1 = {bias[1], bias[1], bias[1], bias[1]};
        f32x4 acc2 = {bias[2], bias[2], bias[2], bias[2]};
        f32x4 acc3 = {bias[3], bias[3], bias[3], bias[3]};
        acc0 = __builtin_amdgcn_mfma_f32_16x16x32_bf16(a0, bf[0][0], acc0, 0, 0, 0);
        acc0 = __builtin_amdgcn_mfma_f32_16x16x32_bf16(a1, bf[0][1], acc0, 0, 0, 0);
        acc0 = __builtin_amdgcn_mfma_f32_16x16x32_bf16(a2, bf[0][2], acc0, 0, 0, 0);
        acc0 = __builtin_amdgcn_mfma_f32_16x16x32_bf16(a3, bf[0][3], acc0, 0, 0, 0);
        acc1 = __builtin_amdgcn_mfma_f32_16x16x32_bf16(a0, bf[1][0], acc1, 0, 0, 0);
        acc1 = __builtin_amdgcn_mfma_f32_16x16x32_bf16(a1, bf[1][1], acc1, 0, 0, 0);
        acc1 = __builtin_amdgcn_mfma_f32_16x16x32_bf16(a2, bf[1][2], acc1, 0, 0, 0);
        acc1 = __builtin_amdgcn_mfma_f32_16x16x32_bf16(a3, bf[1][3], acc1, 0, 0, 0);
        acc2 = __builtin_amdgcn_mfma_f32_16x16x32_bf16(a0, bf[2][0], acc2, 0, 0, 0);
        acc2 = __builtin_amdgcn_mfma_f32_16x16x32_bf16(a1, bf[2][1], acc2, 0, 0, 0);
        acc2 = __builtin_amdgcn_mfma_f32_16x16x32_bf16(a2, bf[2][2], acc2, 0, 0, 0);
        acc2 = __builtin_amdgcn_mfma_f32_16x16x32_bf16(a3, bf[2][3], acc2, 0, 0, 0);
        acc3 = __builtin_amdgcn_mfma_f32_16x16x32_bf16(a0, bf[3][0], acc3, 0, 0, 0);
        acc3 = __builtin_amdgcn_mfma_f32_16x16x32_bf16(a1, bf[3][1], acc3, 0, 0, 0);
        acc3 = __builtin_amdgcn_mfma_f32_16x16x32_bf16(a2, bf[3][2], acc3, 0, 0, 0);
        acc3 = __builtin_amdgcn_mfma_f32_16x16x32_bf16(a3, bf[3][3], acc3, 0, 0, 0);

        float ss[4];
        #pragma unroll
        for (int r = 0; r < 4; ++r)
            ss[r] = acc0[r] * acc0[r] + acc1[r] * acc1[r]
                  + acc2[r] * acc2[r] + acc3[r] * acc3[r];
        #pragma unroll
        for (int msk = 1; msk <= 8; msk <<= 1) {
            ss[0] += __shfl_xor(ss[0], msk);
            ss[1] += __shfl_xor(ss[1], msk);
            ss[2] += __shfl_xor(ss[2], msk);
            ss[3] += __shfl_xor(ss[3], msk);
        }
        #pragma unroll
        for (int r = 0; r < 4; ++r) {
            int nr = n0 + q * 4 + r;
            int dr = __shfl(deg + extra, q * 4 + r);
            if (nr < N) {
                float rin = 1.0f / fmaxf(sqrtf(ss[r]), 1e-12f);
                const float* hp = &h[(size_t)nr * DF + c];
                float hv0 = hp[0], hv1 = hp[16], hv2 = hp[32], hv3 = hp[48];
                bool up = dr > 0;
                float o0 = hv0 + (up ? fmaxf(acc0[r] * rin, 0.f) : hv0);
                float o1 = hv1 + (up ? fmaxf(acc1[r] * rin, 0.f) : hv1);
                float o2 = hv2 + (up ? fmaxf(acc2[r] * rin, 0.f) : hv2);
                float o3 = hv3 + (up ? fmaxf(acc3[r] * rin, 0.f) : hv3);
                float* op = &out[(size_t)nr * DF + c];
                op[0] = o0; op[16] = o1; op[32] = o2; op[48] = o3;
            }
        }
    }
}

extern "C" void kernel_launch(void* const* d_in, const int* in_sizes, int n_in,
                              void* d_out, int out_size, void* d_ws, size_t ws_size,
                              hipStream_t stream) {
    const float* h   = (const float*)d_in[0];
    const float* W   = (const float*)d_in[1];
    const float* b   = (const float*)d_in[2];
    const int*   src = (const int*)d_in[3];
    const int*   dst = (const int*)d_in[4];
    float* out = (float*)d_out;

    const int N = in_sizes[0] / DF;
    const int E = in_sizes[3];

    // workspace carve (16B-aligned); hbs has N+1 rows per slice (zero row)
    int* cnt    = (int*)d_ws;                               // N
    int* ovfcnt = cnt + N;                                  // 1
    int* gcur   = cnt + ((N + 31) & ~15);                   // NB
    int* ell    = gcur + ((NB + 15) & ~15);                 // N*ELLK
    unsigned short* hbs  = (unsigned short*)(ell + (((size_t)N * ELLK + 15) & ~(size_t)15));
    unsigned short* csum = hbs + (((size_t)(N + 1) * DF + 15) & ~(size_t)15);
    unsigned* pairs = (unsigned*)(csum + (((size_t)N * DF + 15) & ~(size_t)15));
    int* ovf    = (int*)(pairs + (size_t)NB * BSTR);
    size_t used = (size_t)((char*)ovf - (char*)d_ws);
    int ovfcap  = (ws_size > used + 64) ? (int)((ws_size - used) / 8 - 4) : 0;

    // K1: bf16 slice-major conversion + zero row + cursor zeroing
    conv_zero<<<(N * 8 + 255) / 256, 256, 0, stream>>>(h, hbs, gcur, ovfcnt, N);

    // K2a: bin edges into dst-range buckets (streaming writes)
    bin_edges<<<(E + EPT * 256 - 1) / (EPT * 256), 256, 0, stream>>>(
        src, dst, gcur, pairs, ovf, ovfcnt, ovfcap, E, N);

    // K2b: LDS-staged ELL build per bucket (coalesced, permuted cols)
    build_ell<<<NB, 256, 0, stream>>>(pairs, gcur, cnt, ell, ovf, ovfcnt, ovfcap, N);

    // K3: feature-sliced gather (4 slices x 16 feats)
    gather_slice<<<2048, 512, 0, stream>>>(hbs, cnt, ell, csum, N);

    // K4: MFMA update
    sage_update_mfma<<<512, 256, 0, stream>>>(
        h, W, b, cnt, hbs, csum, ovf, ovfcnt, ovfcap, out, N);
}